// Round 1
// baseline (282.201 us; speedup 1.0000x reference)
//
#include <hip/hip_runtime.h>

#define THREADS 256
#define NBLOCKS 1568                 // 1568*256 == 2048*14*14 == 401408 cells exactly
#define NCELLS  401408

enum { A_COORD = 0, A_CONF, A_NOOBJ1, A_NOOBJ2, A_NNOOBJ, A_N1, A_N2, A_CLS1, A_CLS2, NACC };

__device__ __forceinline__ float wave_reduce_sum(float v) {
#pragma unroll
    for (int m = 1; m < 64; m <<= 1) v += __shfl_xor(v, m, 64);
    return v;
}

__global__ __launch_bounds__(THREADS) void yolo_main(const float* __restrict__ pred,
                                                     const float* __restrict__ targ,
                                                     float* __restrict__ partial) {
    const int g    = blockIdx.x * THREADS + threadIdx.x;   // cell index, exact cover
    const int lane = threadIdx.x & 63;
    const int within = g % 196;        // S*S = 196
    const int jy = within / 14;        // cell_y (dim 1)
    const int ix = within % 14;        // cell_x (dim 2)
    const size_t base = (size_t)g * 90;

    float acc[NACC];
#pragma unroll
    for (int k = 0; k < NACC; ++k) acc[k] = 0.0f;

    // Loads needed by every cell: target conf, pred conf1, pred conf2
    const float tc  = targ[base + 4];
    const float pc1 = pred[base + 4];
    const float pc2 = pred[base + 9];

    acc[A_NOOBJ2] = pc2 * pc2;                 // mean over ALL cells (unmasked)

    const bool obj = (tc == 1.0f);
    int branch = 0;                            // 1 => resp1 (box1 responsible)

    if (tc == 0.0f) {                          // noobj
        acc[A_NOOBJ1] = pc1 * pc1;
        acc[A_NNOOBJ] = 1.0f;
    }

    if (obj) {
        // Extra loads only for obj lanes (~5%) — predicated, sector-granular
        const float px1 = pred[base + 0], py1 = pred[base + 1];
        const float pw1 = pred[base + 2], ph1 = pred[base + 3];
        const float px2 = pred[base + 5], py2 = pred[base + 6];
        const float pw2 = pred[base + 7], ph2 = pred[base + 8];
        const float tx  = targ[base + 0], ty  = targ[base + 1];
        const float tw  = targ[base + 2], th  = targ[base + 3];

        const float fi = (float)ix, fj = (float)jy;
        const float xt = (fi + tx) / 14.0f, yt = (fj + ty) / 14.0f;

        // IOU box1 vs target (image coords)
        const float xa = (fi + px1) / 14.0f, ya = (fj + py1) / 14.0f;
        float ix0 = fmaxf(xa - pw1 * 0.5f, xt - tw * 0.5f);
        float iy0 = fmaxf(ya - ph1 * 0.5f, yt - th * 0.5f);
        float ix1 = fminf(xa + pw1 * 0.5f, xt + tw * 0.5f);
        float iy1 = fminf(ya + ph1 * 0.5f, yt + th * 0.5f);
        float inter = fmaxf(ix1 - ix0, 0.0f) * fmaxf(iy1 - iy0, 0.0f);
        const float iou1 = inter / (pw1 * ph1 + tw * th - inter + 1e-6f);

        // IOU box2 vs target
        const float xb = (fi + px2) / 14.0f, yb = (fj + py2) / 14.0f;
        ix0 = fmaxf(xb - pw2 * 0.5f, xt - tw * 0.5f);
        iy0 = fmaxf(yb - ph2 * 0.5f, yt - th * 0.5f);
        ix1 = fminf(xb + pw2 * 0.5f, xt + tw * 0.5f);
        iy1 = fminf(yb + ph2 * 0.5f, yt + th * 0.5f);
        inter = fmaxf(ix1 - ix0, 0.0f) * fmaxf(iy1 - iy0, 0.0f);
        const float iou2 = inter / (pw2 * ph2 + tw * th - inter + 1e-6f);

        const bool r1 = (iou1 >= iou2);
        branch = r1 ? 1 : 0;

        const float bx = r1 ? px1 : px2, by = r1 ? py1 : py2;
        const float bw = r1 ? pw1 : pw2, bh = r1 ? ph1 : ph2;
        const float bc = r1 ? pc1 : pc2, oc = r1 ? pc2 : pc1;
        const float biou = r1 ? iou1 : iou2;

        const float dw = sqrtf(fmaxf(bw, 1e-8f)) - sqrtf(fmaxf(tw, 1e-8f));
        const float dh = sqrtf(fmaxf(bh, 1e-8f)) - sqrtf(fmaxf(th, 1e-8f));
        acc[A_COORD] = (bx - tx) * (bx - tx) + (by - ty) * (by - ty) + dw * dw + dh * dh;
        acc[A_CONF]  = (bc - biou) * (bc - biou) + oc * oc;
        if (r1) acc[A_N1] = 1.0f; else acc[A_N2] = 1.0f;
    }

    // Class loss: wave-cooperative, coalesced reads of the 80-class spans.
    unsigned long long mask = __ballot(obj);
    while (mask) {
        const int src = __ffsll(mask) - 1;
        mask &= mask - 1;
        const int nsrc = __shfl(g, src, 64);
        const int br   = __shfl(branch, src, 64);
        const float* __restrict__ pc = pred + (size_t)nsrc * 90 + 10;
        const float* __restrict__ tl = targ + (size_t)nsrc * 90 + 10;
        float d = pc[lane] - tl[lane];
        float v = d * d;
        if (lane < 16) {
            const float d2 = pc[64 + lane] - tl[64 + lane];
            v += d2 * d2;
        }
        if (br) acc[A_CLS1] += v; else acc[A_CLS2] += v;
    }

    // Block reduction: butterfly within wave, LDS across the 4 waves.
    __shared__ float red[4][NACC];
    const int wave = threadIdx.x >> 6;
#pragma unroll
    for (int k = 0; k < NACC; ++k) {
        const float r = wave_reduce_sum(acc[k]);
        if (lane == 0) red[wave][k] = r;
    }
    __syncthreads();
    if (threadIdx.x < NACC) {
        const float s = red[0][threadIdx.x] + red[1][threadIdx.x] +
                        red[2][threadIdx.x] + red[3][threadIdx.x];
        partial[threadIdx.x * NBLOCKS + blockIdx.x] = s;   // [NACC][NBLOCKS]
    }
}

__global__ __launch_bounds__(256) void yolo_finalize(const float* __restrict__ partial,
                                                     float* __restrict__ out) {
    __shared__ float red[4];
    __shared__ float sums[NACC];
    const int lane = threadIdx.x & 63;
    const int wave = threadIdx.x >> 6;

    for (int k = 0; k < NACC; ++k) {
        float s = 0.0f;
        for (int idx = threadIdx.x; idx < NBLOCKS; idx += 256)
            s += partial[k * NBLOCKS + idx];
        s = wave_reduce_sum(s);
        if (lane == 0) red[wave] = s;
        __syncthreads();
        if (threadIdx.x == 0) sums[k] = red[0] + red[1] + red[2] + red[3];
        __syncthreads();
    }

    if (threadIdx.x == 0) {
        const float coord = 5.0f * sums[A_COORD];
        float conf = sums[A_CONF];
        const float nno = sums[A_NNOOBJ];
        const float noobj1 = sums[A_NOOBJ1] / fmaxf(nno, 1.0f);
        const float noobj2 = sums[A_NOOBJ2] / (float)NCELLS;   // mean over B*S*S
        if (nno > 0.0f) conf += 0.5f * (noobj1 + noobj2);
        const float n1 = sums[A_N1], n2 = sums[A_N2];
        float cls = 0.0f;
        if (n1 > 0.0f) cls += sums[A_CLS1] / fmaxf(n1 * 80.0f, 1.0f);
        if (n2 > 0.0f) cls += sums[A_CLS2] / fmaxf(n2 * 80.0f, 1.0f);
        out[0] = (coord + conf + cls) / 2048.0f;
    }
}

extern "C" void kernel_launch(void* const* d_in, const int* in_sizes, int n_in,
                              void* d_out, int out_size, void* d_ws, size_t ws_size,
                              hipStream_t stream) {
    const float* pred = (const float*)d_in[0];
    const float* targ = (const float*)d_in[1];
    float* partial = (float*)d_ws;      // needs NACC*NBLOCKS*4 = 56448 bytes
    float* out = (float*)d_out;

    yolo_main<<<NBLOCKS, THREADS, 0, stream>>>(pred, targ, partial);
    yolo_finalize<<<1, 256, 0, stream>>>(partial, out);
}

// Round 3
// 265.786 us; speedup vs baseline: 1.0618x; 1.0618x over previous
//
#include <hip/hip_runtime.h>

#define THREADS 256
#define NBLOCKS 1568                 // 1568*256 == 2048*14*14 == 401408 cells exactly
#define NCELLS  401408

enum { A_COORD = 0, A_CONF, A_NOOBJ1, A_NOOBJ2, A_NNOOBJ, A_N1, A_N2, A_CLS1, A_CLS2, NACC };

typedef float vf2 __attribute__((ext_vector_type(2)));   // native clang vector — OK for nontemporal builtin

__device__ __forceinline__ float wave_reduce_sum(float v) {
#pragma unroll
    for (int m = 1; m < 64; m <<= 1) v += __shfl_xor(v, m, 64);
    return v;
}

__device__ __forceinline__ float ntl(const float* p) { return __builtin_nontemporal_load(p); }
__device__ __forceinline__ vf2 ntl2(const float* p) {
    const vf2* q = (const vf2*)p;                // 8B-aligned by construction
    return __builtin_nontemporal_load(q);
}

__global__ __launch_bounds__(THREADS) void yolo_main(const float* __restrict__ pred,
                                                     const float* __restrict__ targ,
                                                     float* __restrict__ partial) {
    const int g    = blockIdx.x * THREADS + threadIdx.x;   // cell index, exact cover
    const int lane = threadIdx.x & 63;
    const int within = g % 196;        // S*S = 196
    const int jy = within / 14;        // cell_y (dim 1)
    const int ix = within % 14;        // cell_x (dim 2)
    const size_t base = (size_t)g * 90;

    float acc[NACC];
#pragma unroll
    for (int k = 0; k < NACC; ++k) acc[k] = 0.0f;

    // Loads needed by every cell: target conf, pred conf1, pred conf2
    const float tc  = ntl(targ + base + 4);
    const float pc1 = ntl(pred + base + 4);
    const float pc2 = ntl(pred + base + 9);

    acc[A_NOOBJ2] = pc2 * pc2;                 // mean over ALL cells (unmasked)

    const bool obj = (tc == 1.0f);
    int branch = 0;                            // 1 => resp1 (box1 responsible)

    if (tc == 0.0f) {                          // noobj
        acc[A_NOOBJ1] = pc1 * pc1;
        acc[A_NNOOBJ] = 1.0f;
    }

    if (obj) {
        // Extra loads only for obj lanes (~5%) — predicated, sector-granular.
        // base is even in floats => even float offsets are 8B-aligned.
        const vf2   p1xy = ntl2(pred + base + 0);   // px1, py1
        const vf2   p1wh = ntl2(pred + base + 2);   // pw1, ph1
        const float px2  = ntl(pred + base + 5);
        const vf2   p2yw = ntl2(pred + base + 6);   // py2, pw2
        const float ph2  = ntl(pred + base + 8);
        const vf2   txy  = ntl2(targ + base + 0);
        const vf2   twh  = ntl2(targ + base + 2);

        const float px1 = p1xy.x, py1 = p1xy.y, pw1 = p1wh.x, ph1 = p1wh.y;
        const float py2 = p2yw.x, pw2 = p2yw.y;
        const float tx = txy.x, ty = txy.y, tw = twh.x, th = twh.y;

        const float fi = (float)ix, fj = (float)jy;
        const float xt = (fi + tx) / 14.0f, yt = (fj + ty) / 14.0f;

        // IOU box1 vs target (image coords)
        const float xa = (fi + px1) / 14.0f, ya = (fj + py1) / 14.0f;
        float ix0 = fmaxf(xa - pw1 * 0.5f, xt - tw * 0.5f);
        float iy0 = fmaxf(ya - ph1 * 0.5f, yt - th * 0.5f);
        float ix1 = fminf(xa + pw1 * 0.5f, xt + tw * 0.5f);
        float iy1 = fminf(ya + ph1 * 0.5f, yt + th * 0.5f);
        float inter = fmaxf(ix1 - ix0, 0.0f) * fmaxf(iy1 - iy0, 0.0f);
        const float iou1 = inter / (pw1 * ph1 + tw * th - inter + 1e-6f);

        // IOU box2 vs target
        const float xb = (fi + px2) / 14.0f, yb = (fj + py2) / 14.0f;
        ix0 = fmaxf(xb - pw2 * 0.5f, xt - tw * 0.5f);
        iy0 = fmaxf(yb - ph2 * 0.5f, yt - th * 0.5f);
        ix1 = fminf(xb + pw2 * 0.5f, xt + tw * 0.5f);
        iy1 = fminf(yb + ph2 * 0.5f, yt + th * 0.5f);
        inter = fmaxf(ix1 - ix0, 0.0f) * fmaxf(iy1 - iy0, 0.0f);
        const float iou2 = inter / (pw2 * ph2 + tw * th - inter + 1e-6f);

        const bool r1 = (iou1 >= iou2);
        branch = r1 ? 1 : 0;

        const float bx = r1 ? px1 : px2, by = r1 ? py1 : py2;
        const float bw = r1 ? pw1 : pw2, bh = r1 ? ph1 : ph2;
        const float bc = r1 ? pc1 : pc2, oc = r1 ? pc2 : pc1;
        const float biou = r1 ? iou1 : iou2;

        const float dw = sqrtf(fmaxf(bw, 1e-8f)) - sqrtf(fmaxf(tw, 1e-8f));
        const float dh = sqrtf(fmaxf(bh, 1e-8f)) - sqrtf(fmaxf(th, 1e-8f));
        acc[A_COORD] = (bx - tx) * (bx - tx) + (by - ty) * (by - ty) + dw * dw + dh * dh;
        acc[A_CONF]  = (bc - biou) * (bc - biou) + oc * oc;
        if (r1) acc[A_N1] = 1.0f; else acc[A_N2] = 1.0f;
    }

    // Class loss: wave-cooperative, coalesced float2 reads of the 80-class spans.
    // 80 floats = 40 float2 -> lanes 0..39 each carry one float2 (single instr/matrix).
    unsigned long long mask = __ballot(obj);
    while (mask) {
        const int src = __ffsll(mask) - 1;
        mask &= mask - 1;
        const int nsrc = __shfl(g, src, 64);
        const int br   = __shfl(branch, src, 64);
        float v = 0.0f;
        if (lane < 40) {
            const size_t o = (size_t)nsrc * 90 + 10 + 2 * lane;   // even float offset, 8B aligned
            const vf2 pv = ntl2(pred + o);
            const vf2 tv = ntl2(targ + o);
            const float dx = pv.x - tv.x;
            const float dy = pv.y - tv.y;
            v = dx * dx + dy * dy;
        }
        if (br) acc[A_CLS1] += v; else acc[A_CLS2] += v;
    }

    // Block reduction: butterfly within wave, LDS across the 4 waves.
    __shared__ float red[4][NACC];
    const int wave = threadIdx.x >> 6;
#pragma unroll
    for (int k = 0; k < NACC; ++k) {
        const float r = wave_reduce_sum(acc[k]);
        if (lane == 0) red[wave][k] = r;
    }
    __syncthreads();
    if (threadIdx.x < NACC) {
        const float s = red[0][threadIdx.x] + red[1][threadIdx.x] +
                        red[2][threadIdx.x] + red[3][threadIdx.x];
        partial[threadIdx.x * NBLOCKS + blockIdx.x] = s;   // [NACC][NBLOCKS]
    }
}

__global__ __launch_bounds__(256) void yolo_finalize(const float* __restrict__ partial,
                                                     float* __restrict__ out) {
    __shared__ float red[4];
    __shared__ float sums[NACC];
    const int lane = threadIdx.x & 63;
    const int wave = threadIdx.x >> 6;

    for (int k = 0; k < NACC; ++k) {
        float s = 0.0f;
        for (int idx = threadIdx.x; idx < NBLOCKS; idx += 256)
            s += partial[k * NBLOCKS + idx];
        s = wave_reduce_sum(s);
        if (lane == 0) red[wave] = s;
        __syncthreads();
        if (threadIdx.x == 0) sums[k] = red[0] + red[1] + red[2] + red[3];
        __syncthreads();
    }

    if (threadIdx.x == 0) {
        const float coord = 5.0f * sums[A_COORD];
        float conf = sums[A_CONF];
        const float nno = sums[A_NNOOBJ];
        const float noobj1 = sums[A_NOOBJ1] / fmaxf(nno, 1.0f);
        const float noobj2 = sums[A_NOOBJ2] / (float)NCELLS;   // mean over B*S*S
        if (nno > 0.0f) conf += 0.5f * (noobj1 + noobj2);
        const float n1 = sums[A_N1], n2 = sums[A_N2];
        float cls = 0.0f;
        if (n1 > 0.0f) cls += sums[A_CLS1] / fmaxf(n1 * 80.0f, 1.0f);
        if (n2 > 0.0f) cls += sums[A_CLS2] / fmaxf(n2 * 80.0f, 1.0f);
        out[0] = (coord + conf + cls) / 2048.0f;
    }
}

extern "C" void kernel_launch(void* const* d_in, const int* in_sizes, int n_in,
                              void* d_out, int out_size, void* d_ws, size_t ws_size,
                              hipStream_t stream) {
    const float* pred = (const float*)d_in[0];
    const float* targ = (const float*)d_in[1];
    float* partial = (float*)d_ws;      // needs NACC*NBLOCKS*4 = 56448 bytes
    float* out = (float*)d_out;

    yolo_main<<<NBLOCKS, THREADS, 0, stream>>>(pred, targ, partial);
    yolo_finalize<<<1, 256, 0, stream>>>(partial, out);
}